// Round 2
// 967.809 us; speedup vs baseline: 1.1556x; 1.1556x over previous
//
#include <hip/hip_runtime.h>
#include <math.h>

#define MDIM 128
#define MY 10
#define GAMMA 0.8f
#define KITER 5

__device__ __forceinline__ float bf2f(unsigned short h) {
    return __uint_as_float(((unsigned int)h) << 16);
}
__device__ __forceinline__ unsigned short f2bf(float f) {
    unsigned int u = __float_as_uint(f);
    u += 0x7fffu + ((u >> 16) & 1u);  // round-to-nearest-even
    return (unsigned short)(u >> 16);
}

// ---------------------------------------------------------------- transpose
// X [128][n] -> Y0 fp32 [n][128] and Yh bf16 [n][128]
__global__ void k_transpose(const float* __restrict__ X, float* __restrict__ Y0,
                            unsigned short* __restrict__ Y0h, int n) {
    __shared__ float tile[32][33];
    int r0 = blockIdx.x * 32;
    int f0 = blockIdx.y * 32;
    int tx = threadIdx.x, ty = threadIdx.y;  // 32 x 8
    #pragma unroll
    for (int i = 0; i < 32; i += 8) {
        tile[ty + i][tx] = X[(size_t)(f0 + ty + i) * n + (r0 + tx)];
    }
    __syncthreads();
    #pragma unroll
    for (int i = 0; i < 32; i += 8) {
        float v = tile[tx][ty + i];
        Y0[(size_t)(r0 + ty + i) * MDIM + (f0 + tx)] = v;
        Y0h[(size_t)(r0 + ty + i) * MDIM + (f0 + tx)] = f2bf(v);
    }
}

// ---------------------------------------------------------------- Gram matrix
__global__ void k_gram(const float* __restrict__ F, float* __restrict__ FF,
                       float* __restrict__ normAcc) {
    int i = blockIdx.x, j = threadIdx.x;
    float acc = 0.f;
    for (int k = 0; k < MDIM; ++k)
        acc = fmaf(F[k * MDIM + i], F[k * MDIM + j], acc);
    FF[i * MDIM + j] = acc;
    __shared__ float red[MDIM];
    red[j] = acc * acc;
    __syncthreads();
    for (int s = 64; s > 0; s >>= 1) {
        if (j < s) red[j] += red[j + s];
        __syncthreads();
    }
    if (j == 0) atomicAdd(normAcc, red[0]);
}

__global__ void k_gnorm(const float* __restrict__ FF, const float* __restrict__ normAcc,
                        float* __restrict__ G) {
    int idx = blockIdx.x * 256 + threadIdx.x;
    float s = GAMMA / (sqrtf(*normAcc) + 1e-6f);
    G[idx] = FF[idx] * s;
}

// ---------------------------------------------------------------- CSR build
__global__ void k_hist(const int* __restrict__ erow, int* __restrict__ cnt, int E) {
    int e = blockIdx.x * 256 + threadIdx.x;
    if (e < E) atomicAdd(&cnt[erow[e]], 1);
}

__global__ void k_scan1(const int* __restrict__ cnt, int* __restrict__ blockSums, int n) {
    int tid = threadIdx.x;  // 256
    int base = blockIdx.x * 1024 + tid * 4;
    int s = 0;
    if (base + 3 < n) {
        int4 v = *(const int4*)&cnt[base];
        s = v.x + v.y + v.z + v.w;
    } else {
        for (int i = 0; i < 4; ++i)
            if (base + i < n) s += cnt[base + i];
    }
    __shared__ int red[256];
    red[tid] = s;
    __syncthreads();
    for (int st = 128; st > 0; st >>= 1) {
        if (tid < st) red[tid] += red[tid + st];
        __syncthreads();
    }
    if (tid == 0) blockSums[blockIdx.x] = red[0];
}

__global__ void k_scan2(int* __restrict__ blockSums, int* __restrict__ row_off,
                        int nb, int n) {
    __shared__ int s[256];
    int tid = threadIdx.x;  // 256
    int v = (tid < nb) ? blockSums[tid] : 0;
    s[tid] = v;
    __syncthreads();
    for (int off = 1; off < 256; off <<= 1) {
        int t = (tid >= off) ? s[tid - off] : 0;
        __syncthreads();
        s[tid] += t;
        __syncthreads();
    }
    if (tid < nb) blockSums[tid] = s[tid] - v;
    if (tid == 0) row_off[n] = s[255];
}

__global__ void k_scan3(const int* __restrict__ cnt, const int* __restrict__ blockOff,
                        int* __restrict__ row_off, int n) {
    int tid = threadIdx.x;  // 256
    int base = blockIdx.x * 1024 + tid * 4;
    int v[4];
    #pragma unroll
    for (int i = 0; i < 4; ++i) v[i] = (base + i < n) ? cnt[base + i] : 0;
    int local = v[0] + v[1] + v[2] + v[3];
    __shared__ int s[256];
    s[tid] = local;
    __syncthreads();
    for (int off = 1; off < 256; off <<= 1) {
        int t = (tid >= off) ? s[tid - off] : 0;
        __syncthreads();
        s[tid] += t;
        __syncthreads();
    }
    int excl = s[tid] - local + blockOff[blockIdx.x];
    #pragma unroll
    for (int i = 0; i < 4; ++i) {
        if (base + i < n) { row_off[base + i] = excl; excl += v[i]; }
    }
}

// Packed CSR entry: one 8B scattered store per edge instead of two 4B stores
// to different arrays -> halves the scattered cache lines touched.
__global__ void k_scatter(const int* __restrict__ erow, const int* __restrict__ ecol,
                          const float* __restrict__ eval_, int* __restrict__ cursor,
                          int2* __restrict__ csr_cv, int E) {
    int e = blockIdx.x * 256 + threadIdx.x;
    if (e < E) {
        int r = erow[e];
        int pos = atomicAdd(&cursor[r], 1);
        csr_cv[pos] = make_int2(ecol[e], __float_as_int(eval_[e]));
    }
}

// ---------------------------------------------------------------- fused SpMM + dense update
// Phase 1: each 32-lane group gathers 4 rows of SY = S @ Yh into LDS (fp32).
// Phase 2: Yout = (SY tile) @ G + Y0, with G streamed through LDS in 32-row
//          tiles (16 KB) so total LDS = 32 KB -> 5 blocks/CU for latency hiding
//          of the scattered gather. Accumulators persist across G tiles, so the
//          summation order over j (0..127 ascending) is identical to the
//          original spmm->gemm pair (bit-identical results).
// Output: bf16 state for next iter (writeH) or fp32 + fused BN partial stats
//          (writeF, final iter). SY never touches HBM; intermediate fp32 Y is
//          never written.
__global__ void __launch_bounds__(256) k_fused(const unsigned short* __restrict__ Yh,
                                               const int* __restrict__ row_off,
                                               const int2* __restrict__ csr_cv,
                                               const float* __restrict__ G,
                                               const float* __restrict__ Y0,
                                               float* __restrict__ Yout,
                                               unsigned short* __restrict__ Yhout,
                                               float* __restrict__ stats,
                                               int writeH, int writeF, int n) {
    __shared__ float sGt[32 * MDIM];    // 16 KB (one 32-row tile of G)
    __shared__ float sSY[32 * MDIM];    // 16 KB (reused for BN partials at the end)
    int tid = threadIdx.x;
    int ty = tid >> 5;          // group 0..7
    int tx = tid & 31;          // lane-in-group, owns features tx*4..tx*4+3
    int rbase = blockIdx.x * 32;

    // ---- gather phase: group ty handles rows rbase + ty*4 .. +3
    for (int i = 0; i < 4; ++i) {
        int rloc = ty * 4 + i;
        int e0 = row_off[rbase + rloc];
        int e1 = row_off[rbase + rloc + 1];
        float4 a = make_float4(0.f, 0.f, 0.f, 0.f);
        int e = e0;
        for (; e + 4 <= e1; e += 4) {
            int2 p0 = csr_cv[e + 0];
            int2 p1 = csr_cv[e + 1];
            int2 p2 = csr_cv[e + 2];
            int2 p3 = csr_cv[e + 3];
            ushort4 h0 = *(const ushort4*)&Yh[(size_t)p0.x * MDIM + tx * 4];
            ushort4 h1 = *(const ushort4*)&Yh[(size_t)p1.x * MDIM + tx * 4];
            ushort4 h2 = *(const ushort4*)&Yh[(size_t)p2.x * MDIM + tx * 4];
            ushort4 h3 = *(const ushort4*)&Yh[(size_t)p3.x * MDIM + tx * 4];
            float v0 = __int_as_float(p0.y);
            float v1 = __int_as_float(p1.y);
            float v2 = __int_as_float(p2.y);
            float v3 = __int_as_float(p3.y);
            a.x = fmaf(v0, bf2f(h0.x), a.x);
            a.y = fmaf(v0, bf2f(h0.y), a.y);
            a.z = fmaf(v0, bf2f(h0.z), a.z);
            a.w = fmaf(v0, bf2f(h0.w), a.w);
            a.x = fmaf(v1, bf2f(h1.x), a.x);
            a.y = fmaf(v1, bf2f(h1.y), a.y);
            a.z = fmaf(v1, bf2f(h1.z), a.z);
            a.w = fmaf(v1, bf2f(h1.w), a.w);
            a.x = fmaf(v2, bf2f(h2.x), a.x);
            a.y = fmaf(v2, bf2f(h2.y), a.y);
            a.z = fmaf(v2, bf2f(h2.z), a.z);
            a.w = fmaf(v2, bf2f(h2.w), a.w);
            a.x = fmaf(v3, bf2f(h3.x), a.x);
            a.y = fmaf(v3, bf2f(h3.y), a.y);
            a.z = fmaf(v3, bf2f(h3.z), a.z);
            a.w = fmaf(v3, bf2f(h3.w), a.w);
        }
        for (; e < e1; ++e) {
            int2 p = csr_cv[e];
            float v = __int_as_float(p.y);
            ushort4 h = *(const ushort4*)&Yh[(size_t)p.x * MDIM + tx * 4];
            a.x = fmaf(v, bf2f(h.x), a.x);
            a.y = fmaf(v, bf2f(h.y), a.y);
            a.z = fmaf(v, bf2f(h.z), a.z);
            a.w = fmaf(v, bf2f(h.w), a.w);
        }
        // dense phase reads these rows only from the same 32-lane group ->
        // intra-wave ordering suffices, no block barrier needed here.
        *(float4*)&sSY[rloc * MDIM + tx * 4] = a;
    }

    // ---- dense phase: thread computes 4 rows x 4 features, G tiled 32 rows
    size_t r0 = (size_t)rbase + ty * 4;
    int f0 = tx * 4;
    float4 acc[4];
    #pragma unroll
    for (int i = 0; i < 4; ++i) acc[i] = make_float4(0.f, 0.f, 0.f, 0.f);

    for (int jt = 0; jt < MDIM; jt += 32) {
        if (jt) __syncthreads();  // WAR: previous tile fully consumed
        #pragma unroll
        for (int i = 0; i < 4; ++i) {
            int idx = (i * 256 + tid) * 4;  // 4096 floats per tile
            *(float4*)&sGt[idx] = *(const float4*)&G[jt * MDIM + idx];
        }
        __syncthreads();          // RAW: tile loaded
        for (int j = 0; j < 32; j += 4) {
            float4 g0 = *(const float4*)&sGt[(j + 0) * MDIM + f0];
            float4 g1 = *(const float4*)&sGt[(j + 1) * MDIM + f0];
            float4 g2 = *(const float4*)&sGt[(j + 2) * MDIM + f0];
            float4 g3 = *(const float4*)&sGt[(j + 3) * MDIM + f0];
            #pragma unroll
            for (int i = 0; i < 4; ++i) {
                float4 sr = *(const float4*)&sSY[(ty * 4 + i) * MDIM + jt + j];
                acc[i].x = fmaf(sr.x, g0.x, acc[i].x);
                acc[i].y = fmaf(sr.x, g0.y, acc[i].y);
                acc[i].z = fmaf(sr.x, g0.z, acc[i].z);
                acc[i].w = fmaf(sr.x, g0.w, acc[i].w);
                acc[i].x = fmaf(sr.y, g1.x, acc[i].x);
                acc[i].y = fmaf(sr.y, g1.y, acc[i].y);
                acc[i].z = fmaf(sr.y, g1.z, acc[i].z);
                acc[i].w = fmaf(sr.y, g1.w, acc[i].w);
                acc[i].x = fmaf(sr.z, g2.x, acc[i].x);
                acc[i].y = fmaf(sr.z, g2.y, acc[i].y);
                acc[i].z = fmaf(sr.z, g2.z, acc[i].z);
                acc[i].w = fmaf(sr.z, g2.w, acc[i].w);
                acc[i].x = fmaf(sr.w, g3.x, acc[i].x);
                acc[i].y = fmaf(sr.w, g3.y, acc[i].y);
                acc[i].z = fmaf(sr.w, g3.z, acc[i].z);
                acc[i].w = fmaf(sr.w, g3.w, acc[i].w);
            }
        }
    }

    float4 bs = make_float4(0.f, 0.f, 0.f, 0.f);
    float4 bq = make_float4(0.f, 0.f, 0.f, 0.f);
    #pragma unroll
    for (int i = 0; i < 4; ++i) {
        float4 y0 = *(const float4*)&Y0[(r0 + i) * MDIM + f0];
        float4 o;
        o.x = acc[i].x + y0.x;
        o.y = acc[i].y + y0.y;
        o.z = acc[i].z + y0.z;
        o.w = acc[i].w + y0.w;
        if (writeF) {
            *(float4*)&Yout[(r0 + i) * MDIM + f0] = o;
            bs.x += o.x; bs.y += o.y; bs.z += o.z; bs.w += o.w;
            bq.x = fmaf(o.x, o.x, bq.x);
            bq.y = fmaf(o.y, o.y, bq.y);
            bq.z = fmaf(o.z, o.z, bq.z);
            bq.w = fmaf(o.w, o.w, bq.w);
        }
        if (writeH) {
            ushort4 h;
            h.x = f2bf(o.x);
            h.y = f2bf(o.y);
            h.z = f2bf(o.z);
            h.w = f2bf(o.w);
            *(ushort4*)&Yhout[(r0 + i) * MDIM + f0] = h;
        }
    }

    // ---- fused BN partial stats (final iteration only)
    if (writeF) {
        __syncthreads();  // everyone done reading sSY
        *(float4*)&sSY[ty * MDIM + f0] = bs;
        *(float4*)&sSY[8 * MDIM + ty * MDIM + f0] = bq;
        __syncthreads();
        if (tid < MDIM) {
            float a = 0.f, b = 0.f;
            #pragma unroll
            for (int t = 0; t < 8; ++t) {
                a += sSY[t * MDIM + tid];
                b += sSY[8 * MDIM + t * MDIM + tid];
            }
            atomicAdd(&stats[tid], a);
            atomicAdd(&stats[MDIM + tid], b);
        }
    }
}

// ---------------------------------------------------------------- BN finalize
__global__ void k_finalize(const float* __restrict__ stats, const float* __restrict__ B,
                           const float* __restrict__ bnw, const float* __restrict__ bnb,
                           float* __restrict__ Bs, float* __restrict__ cvec, int n) {
    int f = threadIdx.x;
    float inv_n = 1.f / (float)n;
    float mu = stats[f] * inv_n;
    float var = stats[MDIM + f] * inv_n - mu * mu;
    float rs = rsqrtf(var + 1e-5f);
    float sw = rs * bnw[f];
    float cv = bnb[f] - mu * sw;
    __shared__ float red[MDIM];
    for (int o = 0; o < MY; ++o) {
        float b = B[o * MDIM + f];
        Bs[o * MDIM + f] = b * sw;
        red[f] = b * cv;
        __syncthreads();
        for (int s = 64; s > 0; s >>= 1) {
            if (f < s) red[f] += red[f + s];
            __syncthreads();
        }
        if (f == 0) cvec[o] = red[0];
        __syncthreads();
    }
}

// ---------------------------------------------------------------- projection
__global__ void __launch_bounds__(256) k_project(const float* __restrict__ Y,
                                                 const float* __restrict__ Bs,
                                                 const float* __restrict__ cvec,
                                                 float* __restrict__ out, int n) {
    __shared__ float yt[16 * 129];
    __shared__ float sB[MY * 129];
    __shared__ float sc[MY];
    int tid = threadIdx.x;
    size_t rbase = (size_t)blockIdx.x * 16;
    for (int idx = tid; idx < 16 * MDIM; idx += 256) {
        int r = idx >> 7, f = idx & 127;
        yt[r * 129 + f] = Y[(rbase + r) * MDIM + f];
    }
    for (int idx = tid; idx < MY * MDIM; idx += 256) {
        int o = idx >> 7, f = idx & 127;
        sB[o * 129 + f] = Bs[idx];
    }
    if (tid < MY) sc[tid] = cvec[tid];
    __syncthreads();
    if (tid < 16 * MY) {
        int r = tid / MY, o = tid % MY;
        float acc = sc[o];
        for (int f = 0; f < MDIM; ++f)
            acc = fmaf(yt[r * 129 + f], sB[o * 129 + f], acc);
        out[(rbase + r) * MY + o] = acc;
    }
}

// ---------------------------------------------------------------- launch
extern "C" void kernel_launch(void* const* d_in, const int* in_sizes, int n_in,
                              void* d_out, int out_size, void* d_ws, size_t ws_size,
                              hipStream_t stream) {
    const float* X    = (const float*)d_in[0];
    const float* F    = (const float*)d_in[1];
    const float* B    = (const float*)d_in[2];
    const float* bnw  = (const float*)d_in[3];
    const float* bnb  = (const float*)d_in[4];
    const float* ev   = (const float*)d_in[5];
    const int*   erow = (const int*)d_in[6];
    const int*   ecol = (const int*)d_in[7];
    float* out = (float*)d_out;
    const int n = in_sizes[0] / MDIM;  // 100000
    const int E = in_sizes[5];         // 1600000

    char* w = (char*)d_ws;
    size_t off = 0;
    auto carve = [&](size_t bytes) -> void* {
        void* p = w + off;
        off += (bytes + 255) & ~(size_t)255;
        return p;
    };
    float*          Y0    = (float*)carve((size_t)n * MDIM * 4);
    float*          Ycur  = (float*)carve((size_t)n * MDIM * 4);
    unsigned short* Yh_a  = (unsigned short*)carve((size_t)n * MDIM * 2);  // bf16 state ping
    unsigned short* Yh_b  = (unsigned short*)carve((size_t)n * MDIM * 2);  // bf16 state pong
    float* FF        = (float*)carve(MDIM * MDIM * 4);
    float* G         = (float*)carve(MDIM * MDIM * 4);
    int2*  csr_cv    = (int2*)carve((size_t)E * 8);
    int*   row_off   = (int*)carve((size_t)(n + 1) * 4);
    int*   cursor    = (int*)carve((size_t)n * 4);
    int*   cnt       = (int*)carve((size_t)n * 4);
    int*   blockSums = (int*)carve(1024 * 4);
    float* normAcc   = (float*)carve(4);
    float* stats     = (float*)carve(2 * MDIM * 4);
    float* Bs        = (float*)carve(MY * MDIM * 4);
    float* cvec      = (float*)carve(MY * 4);
    (void)ws_size;

    hipMemsetAsync(cnt, 0, (size_t)n * 4, stream);
    hipMemsetAsync(normAcc, 0, 4, stream);
    hipMemsetAsync(stats, 0, 2 * MDIM * 4, stream);

    k_transpose<<<dim3(n / 32, MDIM / 32), dim3(32, 8), 0, stream>>>(X, Y0, Yh_a, n);
    k_gram<<<MDIM, MDIM, 0, stream>>>(F, FF, normAcc);
    k_gnorm<<<MDIM * MDIM / 256, 256, 0, stream>>>(FF, normAcc, G);

    const int nb = (n + 1023) / 1024;
    k_hist<<<(E + 255) / 256, 256, 0, stream>>>(erow, cnt, E);
    k_scan1<<<nb, 256, 0, stream>>>(cnt, blockSums, n);
    k_scan2<<<1, 256, 0, stream>>>(blockSums, row_off, nb, n);
    k_scan3<<<nb, 256, 0, stream>>>(cnt, blockSums, row_off, n);
    hipMemcpyAsync(cursor, row_off, (size_t)n * 4, hipMemcpyDeviceToDevice, stream);
    k_scatter<<<(E + 255) / 256, 256, 0, stream>>>(erow, ecol, ev, cursor, csr_cv, E);

    for (int k = 0; k < KITER; ++k) {
        const unsigned short* hin = (k & 1) ? Yh_b : Yh_a;
        unsigned short*       hout = (k & 1) ? Yh_a : Yh_b;
        int writeH = (k < KITER - 1) ? 1 : 0;
        int writeF = (k == KITER - 1) ? 1 : 0;
        k_fused<<<n / 32, 256, 0, stream>>>(hin, row_off, csr_cv, G, Y0, Ycur, hout,
                                            stats, writeH, writeF, n);
    }

    k_finalize<<<1, MDIM, 0, stream>>>(stats, B, bnw, bnb, Bs, cvec, n);
    k_project<<<n / 16, 256, 0, stream>>>(Ycur, Bs, cvec, out, n);
}

// Round 3
// 920.370 us; speedup vs baseline: 1.2152x; 1.0515x over previous
//
#include <hip/hip_runtime.h>
#include <math.h>

#define MDIM 128
#define MY 10
#define GAMMA 0.8f
#define KITER 5

__device__ __forceinline__ float bf2f(unsigned short h) {
    return __uint_as_float(((unsigned int)h) << 16);
}
__device__ __forceinline__ unsigned short f2bf(float f) {
    unsigned int u = __float_as_uint(f);
    u += 0x7fffu + ((u >> 16) & 1u);  // round-to-nearest-even
    return (unsigned short)(u >> 16);
}

// ---------------------------------------------------------------- transpose
// X [128][n] -> Y0 fp32 [n][128] and Yh bf16 [n][128]
__global__ void k_transpose(const float* __restrict__ X, float* __restrict__ Y0,
                            unsigned short* __restrict__ Y0h, int n) {
    __shared__ float tile[32][33];
    int r0 = blockIdx.x * 32;
    int f0 = blockIdx.y * 32;
    int tx = threadIdx.x, ty = threadIdx.y;  // 32 x 8
    #pragma unroll
    for (int i = 0; i < 32; i += 8) {
        tile[ty + i][tx] = X[(size_t)(f0 + ty + i) * n + (r0 + tx)];
    }
    __syncthreads();
    #pragma unroll
    for (int i = 0; i < 32; i += 8) {
        float v = tile[tx][ty + i];
        Y0[(size_t)(r0 + ty + i) * MDIM + (f0 + tx)] = v;
        Y0h[(size_t)(r0 + ty + i) * MDIM + (f0 + tx)] = f2bf(v);
    }
}

// ---------------------------------------------------------------- Gram matrix
__global__ void k_gram(const float* __restrict__ F, float* __restrict__ FF,
                       float* __restrict__ normAcc) {
    int i = blockIdx.x, j = threadIdx.x;
    float acc = 0.f;
    for (int k = 0; k < MDIM; ++k)
        acc = fmaf(F[k * MDIM + i], F[k * MDIM + j], acc);
    FF[i * MDIM + j] = acc;
    __shared__ float red[MDIM];
    red[j] = acc * acc;
    __syncthreads();
    for (int s = 64; s > 0; s >>= 1) {
        if (j < s) red[j] += red[j + s];
        __syncthreads();
    }
    if (j == 0) atomicAdd(normAcc, red[0]);
}

__global__ void k_gnorm(const float* __restrict__ FF, const float* __restrict__ normAcc,
                        float* __restrict__ G) {
    int idx = blockIdx.x * 256 + threadIdx.x;
    float s = GAMMA / (sqrtf(*normAcc) + 1e-6f);
    G[idx] = FF[idx] * s;
}

// ---------------------------------------------------------------- CSR build
__global__ void k_hist(const int* __restrict__ erow, int* __restrict__ cnt, int E) {
    int e = blockIdx.x * 256 + threadIdx.x;
    if (e < E) atomicAdd(&cnt[erow[e]], 1);
}

__global__ void k_scan1(const int* __restrict__ cnt, int* __restrict__ blockSums, int n) {
    int tid = threadIdx.x;  // 256
    int base = blockIdx.x * 1024 + tid * 4;
    int s = 0;
    if (base + 3 < n) {
        int4 v = *(const int4*)&cnt[base];
        s = v.x + v.y + v.z + v.w;
    } else {
        for (int i = 0; i < 4; ++i)
            if (base + i < n) s += cnt[base + i];
    }
    __shared__ int red[256];
    red[tid] = s;
    __syncthreads();
    for (int st = 128; st > 0; st >>= 1) {
        if (tid < st) red[tid] += red[tid + st];
        __syncthreads();
    }
    if (tid == 0) blockSums[blockIdx.x] = red[0];
}

__global__ void k_scan2(int* __restrict__ blockSums, int* __restrict__ row_off,
                        int nb, int n) {
    __shared__ int s[256];
    int tid = threadIdx.x;  // 256
    int v = (tid < nb) ? blockSums[tid] : 0;
    s[tid] = v;
    __syncthreads();
    for (int off = 1; off < 256; off <<= 1) {
        int t = (tid >= off) ? s[tid - off] : 0;
        __syncthreads();
        s[tid] += t;
        __syncthreads();
    }
    if (tid < nb) blockSums[tid] = s[tid] - v;
    if (tid == 0) row_off[n] = s[255];
}

__global__ void k_scan3(const int* __restrict__ cnt, const int* __restrict__ blockOff,
                        int* __restrict__ row_off, int n) {
    int tid = threadIdx.x;  // 256
    int base = blockIdx.x * 1024 + tid * 4;
    int v[4];
    #pragma unroll
    for (int i = 0; i < 4; ++i) v[i] = (base + i < n) ? cnt[base + i] : 0;
    int local = v[0] + v[1] + v[2] + v[3];
    __shared__ int s[256];
    s[tid] = local;
    __syncthreads();
    for (int off = 1; off < 256; off <<= 1) {
        int t = (tid >= off) ? s[tid - off] : 0;
        __syncthreads();
        s[tid] += t;
        __syncthreads();
    }
    int excl = s[tid] - local + blockOff[blockIdx.x];
    #pragma unroll
    for (int i = 0; i < 4; ++i) {
        if (base + i < n) { row_off[base + i] = excl; excl += v[i]; }
    }
}

// Packed CSR entry: one 8B scattered store per edge instead of two 4B stores
// to different arrays -> halves the scattered cache lines touched.
__global__ void k_scatter(const int* __restrict__ erow, const int* __restrict__ ecol,
                          const float* __restrict__ eval_, int* __restrict__ cursor,
                          int2* __restrict__ csr_cv, int E) {
    int e = blockIdx.x * 256 + threadIdx.x;
    if (e < E) {
        int r = erow[e];
        int pos = atomicAdd(&cursor[r], 1);
        csr_cv[pos] = make_int2(ecol[e], __float_as_int(eval_[e]));
    }
}

// ---------------------------------------------------------------- fused SpMM + dense update
// Phase 1: each 32-lane group gathers 4 rows of SY = S @ Yh into LDS (fp32).
// Phase 2: Yout = (SY tile) @ G + Y0 with G read directly from global memory
//          (64 KB, fully L2-resident, every wave sweeps the same lines).
// LDS = 16 KB (sSY only) -> 8 blocks/CU = 32 waves/CU (hardware max) for
// latency hiding of the scattered gather, which counters show is the limiter
// (VALUBusy 30%, HBM 21%, occupancy-capped at 20 waves by the old 32 KB LDS).
// The non-final path now has ZERO barriers: dense reads of sSY touch only the
// 4 rows written by the same 32-lane group (same wave64) -> intra-wave
// lgkmcnt ordering suffices. Math order identical -> bit-identical results.
__global__ void __launch_bounds__(256, 8) k_fused(const unsigned short* __restrict__ Yh,
                                                  const int* __restrict__ row_off,
                                                  const int2* __restrict__ csr_cv,
                                                  const float* __restrict__ G,
                                                  const float* __restrict__ Y0,
                                                  float* __restrict__ Yout,
                                                  unsigned short* __restrict__ Yhout,
                                                  float* __restrict__ stats,
                                                  int writeH, int writeF, int n) {
    __shared__ float sSY[32 * MDIM];    // 16 KB (reused for BN partials at the end)
    int tid = threadIdx.x;
    int ty = tid >> 5;          // group 0..7
    int tx = tid & 31;          // lane-in-group, owns features tx*4..tx*4+3
    int rbase = blockIdx.x * 32;

    // ---- gather phase: group ty handles rows rbase + ty*4 .. +3
    for (int i = 0; i < 4; ++i) {
        int rloc = ty * 4 + i;
        int e0 = row_off[rbase + rloc];
        int e1 = row_off[rbase + rloc + 1];
        float4 a = make_float4(0.f, 0.f, 0.f, 0.f);
        int e = e0;
        for (; e + 4 <= e1; e += 4) {
            int2 p0 = csr_cv[e + 0];
            int2 p1 = csr_cv[e + 1];
            int2 p2 = csr_cv[e + 2];
            int2 p3 = csr_cv[e + 3];
            ushort4 h0 = *(const ushort4*)&Yh[(size_t)p0.x * MDIM + tx * 4];
            ushort4 h1 = *(const ushort4*)&Yh[(size_t)p1.x * MDIM + tx * 4];
            ushort4 h2 = *(const ushort4*)&Yh[(size_t)p2.x * MDIM + tx * 4];
            ushort4 h3 = *(const ushort4*)&Yh[(size_t)p3.x * MDIM + tx * 4];
            float v0 = __int_as_float(p0.y);
            float v1 = __int_as_float(p1.y);
            float v2 = __int_as_float(p2.y);
            float v3 = __int_as_float(p3.y);
            a.x = fmaf(v0, bf2f(h0.x), a.x);
            a.y = fmaf(v0, bf2f(h0.y), a.y);
            a.z = fmaf(v0, bf2f(h0.z), a.z);
            a.w = fmaf(v0, bf2f(h0.w), a.w);
            a.x = fmaf(v1, bf2f(h1.x), a.x);
            a.y = fmaf(v1, bf2f(h1.y), a.y);
            a.z = fmaf(v1, bf2f(h1.z), a.z);
            a.w = fmaf(v1, bf2f(h1.w), a.w);
            a.x = fmaf(v2, bf2f(h2.x), a.x);
            a.y = fmaf(v2, bf2f(h2.y), a.y);
            a.z = fmaf(v2, bf2f(h2.z), a.z);
            a.w = fmaf(v2, bf2f(h2.w), a.w);
            a.x = fmaf(v3, bf2f(h3.x), a.x);
            a.y = fmaf(v3, bf2f(h3.y), a.y);
            a.z = fmaf(v3, bf2f(h3.z), a.z);
            a.w = fmaf(v3, bf2f(h3.w), a.w);
        }
        for (; e < e1; ++e) {
            int2 p = csr_cv[e];
            float v = __int_as_float(p.y);
            ushort4 h = *(const ushort4*)&Yh[(size_t)p.x * MDIM + tx * 4];
            a.x = fmaf(v, bf2f(h.x), a.x);
            a.y = fmaf(v, bf2f(h.y), a.y);
            a.z = fmaf(v, bf2f(h.z), a.z);
            a.w = fmaf(v, bf2f(h.w), a.w);
        }
        // dense phase reads these rows only from the same 32-lane group ->
        // intra-wave ordering suffices, no block barrier needed.
        *(float4*)&sSY[rloc * MDIM + tx * 4] = a;
    }

    // ---- dense phase: thread computes 4 rows x 4 features, G from L1/L2
    size_t r0 = (size_t)rbase + ty * 4;
    int f0 = tx * 4;
    float4 acc[4];
    #pragma unroll
    for (int i = 0; i < 4; ++i) acc[i] = make_float4(0.f, 0.f, 0.f, 0.f);

    for (int j = 0; j < MDIM; j += 4) {
        float4 g0 = *(const float4*)&G[(j + 0) * MDIM + f0];
        float4 g1 = *(const float4*)&G[(j + 1) * MDIM + f0];
        float4 g2 = *(const float4*)&G[(j + 2) * MDIM + f0];
        float4 g3 = *(const float4*)&G[(j + 3) * MDIM + f0];
        #pragma unroll
        for (int i = 0; i < 4; ++i) {
            float4 sr = *(const float4*)&sSY[(ty * 4 + i) * MDIM + j];
            acc[i].x = fmaf(sr.x, g0.x, acc[i].x);
            acc[i].y = fmaf(sr.x, g0.y, acc[i].y);
            acc[i].z = fmaf(sr.x, g0.z, acc[i].z);
            acc[i].w = fmaf(sr.x, g0.w, acc[i].w);
            acc[i].x = fmaf(sr.y, g1.x, acc[i].x);
            acc[i].y = fmaf(sr.y, g1.y, acc[i].y);
            acc[i].z = fmaf(sr.y, g1.z, acc[i].z);
            acc[i].w = fmaf(sr.y, g1.w, acc[i].w);
            acc[i].x = fmaf(sr.z, g2.x, acc[i].x);
            acc[i].y = fmaf(sr.z, g2.y, acc[i].y);
            acc[i].z = fmaf(sr.z, g2.z, acc[i].z);
            acc[i].w = fmaf(sr.z, g2.w, acc[i].w);
            acc[i].x = fmaf(sr.w, g3.x, acc[i].x);
            acc[i].y = fmaf(sr.w, g3.y, acc[i].y);
            acc[i].z = fmaf(sr.w, g3.z, acc[i].z);
            acc[i].w = fmaf(sr.w, g3.w, acc[i].w);
        }
    }

    float4 bs = make_float4(0.f, 0.f, 0.f, 0.f);
    float4 bq = make_float4(0.f, 0.f, 0.f, 0.f);
    #pragma unroll
    for (int i = 0; i < 4; ++i) {
        float4 y0 = *(const float4*)&Y0[(r0 + i) * MDIM + f0];
        float4 o;
        o.x = acc[i].x + y0.x;
        o.y = acc[i].y + y0.y;
        o.z = acc[i].z + y0.z;
        o.w = acc[i].w + y0.w;
        if (writeF) {
            *(float4*)&Yout[(r0 + i) * MDIM + f0] = o;
            bs.x += o.x; bs.y += o.y; bs.z += o.z; bs.w += o.w;
            bq.x = fmaf(o.x, o.x, bq.x);
            bq.y = fmaf(o.y, o.y, bq.y);
            bq.z = fmaf(o.z, o.z, bq.z);
            bq.w = fmaf(o.w, o.w, bq.w);
        }
        if (writeH) {
            ushort4 h;
            h.x = f2bf(o.x);
            h.y = f2bf(o.y);
            h.z = f2bf(o.z);
            h.w = f2bf(o.w);
            *(ushort4*)&Yhout[(r0 + i) * MDIM + f0] = h;
        }
    }

    // ---- fused BN partial stats (final iteration only)
    if (writeF) {
        __syncthreads();  // everyone done reading sSY
        *(float4*)&sSY[ty * MDIM + f0] = bs;
        *(float4*)&sSY[8 * MDIM + ty * MDIM + f0] = bq;
        __syncthreads();
        if (tid < MDIM) {
            float a = 0.f, b = 0.f;
            #pragma unroll
            for (int t = 0; t < 8; ++t) {
                a += sSY[t * MDIM + tid];
                b += sSY[8 * MDIM + t * MDIM + tid];
            }
            atomicAdd(&stats[tid], a);
            atomicAdd(&stats[MDIM + tid], b);
        }
    }
}

// ---------------------------------------------------------------- BN finalize
__global__ void k_finalize(const float* __restrict__ stats, const float* __restrict__ B,
                           const float* __restrict__ bnw, const float* __restrict__ bnb,
                           float* __restrict__ Bs, float* __restrict__ cvec, int n) {
    int f = threadIdx.x;
    float inv_n = 1.f / (float)n;
    float mu = stats[f] * inv_n;
    float var = stats[MDIM + f] * inv_n - mu * mu;
    float rs = rsqrtf(var + 1e-5f);
    float sw = rs * bnw[f];
    float cv = bnb[f] - mu * sw;
    __shared__ float red[MDIM];
    for (int o = 0; o < MY; ++o) {
        float b = B[o * MDIM + f];
        Bs[o * MDIM + f] = b * sw;
        red[f] = b * cv;
        __syncthreads();
        for (int s = 64; s > 0; s >>= 1) {
            if (f < s) red[f] += red[f + s];
            __syncthreads();
        }
        if (f == 0) cvec[o] = red[0];
        __syncthreads();
    }
}

// ---------------------------------------------------------------- projection
__global__ void __launch_bounds__(256) k_project(const float* __restrict__ Y,
                                                 const float* __restrict__ Bs,
                                                 const float* __restrict__ cvec,
                                                 float* __restrict__ out, int n) {
    __shared__ float yt[16 * 129];
    __shared__ float sB[MY * 129];
    __shared__ float sc[MY];
    int tid = threadIdx.x;
    size_t rbase = (size_t)blockIdx.x * 16;
    for (int idx = tid; idx < 16 * MDIM; idx += 256) {
        int r = idx >> 7, f = idx & 127;
        yt[r * 129 + f] = Y[(rbase + r) * MDIM + f];
    }
    for (int idx = tid; idx < MY * MDIM; idx += 256) {
        int o = idx >> 7, f = idx & 127;
        sB[o * 129 + f] = Bs[idx];
    }
    if (tid < MY) sc[tid] = cvec[tid];
    __syncthreads();
    if (tid < 16 * MY) {
        int r = tid / MY, o = tid % MY;
        float acc = sc[o];
        for (int f = 0; f < MDIM; ++f)
            acc = fmaf(yt[r * 129 + f], sB[o * 129 + f], acc);
        out[(rbase + r) * MY + o] = acc;
    }
}

// ---------------------------------------------------------------- launch
extern "C" void kernel_launch(void* const* d_in, const int* in_sizes, int n_in,
                              void* d_out, int out_size, void* d_ws, size_t ws_size,
                              hipStream_t stream) {
    const float* X    = (const float*)d_in[0];
    const float* F    = (const float*)d_in[1];
    const float* B    = (const float*)d_in[2];
    const float* bnw  = (const float*)d_in[3];
    const float* bnb  = (const float*)d_in[4];
    const float* ev   = (const float*)d_in[5];
    const int*   erow = (const int*)d_in[6];
    const int*   ecol = (const int*)d_in[7];
    float* out = (float*)d_out;
    const int n = in_sizes[0] / MDIM;  // 100000
    const int E = in_sizes[5];         // 1600000

    char* w = (char*)d_ws;
    size_t off = 0;
    auto carve = [&](size_t bytes) -> void* {
        void* p = w + off;
        off += (bytes + 255) & ~(size_t)255;
        return p;
    };
    float*          Y0    = (float*)carve((size_t)n * MDIM * 4);
    float*          Ycur  = (float*)carve((size_t)n * MDIM * 4);
    unsigned short* Yh_a  = (unsigned short*)carve((size_t)n * MDIM * 2);  // bf16 state ping
    unsigned short* Yh_b  = (unsigned short*)carve((size_t)n * MDIM * 2);  // bf16 state pong
    float* FF        = (float*)carve(MDIM * MDIM * 4);
    float* G         = (float*)carve(MDIM * MDIM * 4);
    int2*  csr_cv    = (int2*)carve((size_t)E * 8);
    int*   row_off   = (int*)carve((size_t)(n + 1) * 4);
    int*   cursor    = (int*)carve((size_t)n * 4);
    int*   cnt       = (int*)carve((size_t)n * 4);
    int*   blockSums = (int*)carve(1024 * 4);
    float* normAcc   = (float*)carve(4);
    float* stats     = (float*)carve(2 * MDIM * 4);
    float* Bs        = (float*)carve(MY * MDIM * 4);
    float* cvec      = (float*)carve(MY * 4);
    (void)ws_size;

    hipMemsetAsync(cnt, 0, (size_t)n * 4, stream);
    hipMemsetAsync(normAcc, 0, 4, stream);
    hipMemsetAsync(stats, 0, 2 * MDIM * 4, stream);

    k_transpose<<<dim3(n / 32, MDIM / 32), dim3(32, 8), 0, stream>>>(X, Y0, Yh_a, n);
    k_gram<<<MDIM, MDIM, 0, stream>>>(F, FF, normAcc);
    k_gnorm<<<MDIM * MDIM / 256, 256, 0, stream>>>(FF, normAcc, G);

    const int nb = (n + 1023) / 1024;
    k_hist<<<(E + 255) / 256, 256, 0, stream>>>(erow, cnt, E);
    k_scan1<<<nb, 256, 0, stream>>>(cnt, blockSums, n);
    k_scan2<<<1, 256, 0, stream>>>(blockSums, row_off, nb, n);
    k_scan3<<<nb, 256, 0, stream>>>(cnt, blockSums, row_off, n);
    hipMemcpyAsync(cursor, row_off, (size_t)n * 4, hipMemcpyDeviceToDevice, stream);
    k_scatter<<<(E + 255) / 256, 256, 0, stream>>>(erow, ecol, ev, cursor, csr_cv, E);

    for (int k = 0; k < KITER; ++k) {
        const unsigned short* hin = (k & 1) ? Yh_b : Yh_a;
        unsigned short*       hout = (k & 1) ? Yh_a : Yh_b;
        int writeH = (k < KITER - 1) ? 1 : 0;
        int writeF = (k == KITER - 1) ? 1 : 0;
        k_fused<<<n / 32, 256, 0, stream>>>(hin, row_off, csr_cv, G, Y0, Ycur, hout,
                                            stats, writeH, writeF, n);
    }

    k_finalize<<<1, MDIM, 0, stream>>>(stats, B, bnw, bnb, Bs, cvec, n);
    k_project<<<n / 16, 256, 0, stream>>>(Ycur, Bs, cvec, out, n);
}